// Round 9
// baseline (689.829 us; speedup 1.0000x reference)
//
#include <hip/hip_runtime.h>
#include <math.h>

#define D_MODEL 4096
#define NEXP    64
#define TOPK    8
#define NTOK    16384        // 4 * 4096
#define BLK_TOK 64
#define NTHR    1024         // 16 waves = 4 token-stripes x 4 K-chunks
#define KC      1024         // d per K-chunk (per wave)

#define W2_USHORTS (NEXP * D_MODEL * 2)      // 524288 ushorts = 1 MB (hi+lo bf16)

typedef __attribute__((ext_vector_type(8))) short bf16x8;   // 8 bf16 = 4 VGPRs
typedef __attribute__((ext_vector_type(4))) float f32x4;

// bf16 round-to-nearest-even of fp32
__device__ inline unsigned b16rne(float f) {
    unsigned u = __float_as_uint(f);
    return (u + 0x7FFFu + ((u >> 16) & 1u)) >> 16;   // low 16 bits valid
}

// W2 layout: [kb:512][e:64][h:2][i:8] bf16, kb = d>>3, i = d&7.
// W2[((kb*64+e)*2+h)*8+i] = bf16 of (h==0 ? hi : lo) part of W[e][kb*8+i].
// kb-row stride = 1024 ushorts; per-32d K-step stride = 4096 ushorts (R8-verified).
// Rebuilt every iteration: harness re-poisons the 1 GiB workspace (the 161 us
// fillBuffer dispatches in R8's top-5), so nothing can be cached across runs.
__global__ void prep_kernel(const float* __restrict__ W, unsigned short* __restrict__ W2) {
    int o = blockIdx.x * 256 + threadIdx.x;    // 262144 = 512 kb x 64 e x 8 i
    int i  = o & 7;
    int e  = (o >> 3) & 63;
    int kb = o >> 9;
    float w = W[(size_t)e * D_MODEL + kb * 8 + i];
    unsigned hb = b16rne(w);
    float hf = __uint_as_float(hb << 16);
    unsigned lb = b16rne(w - hf);
    size_t base = ((size_t)(kb * 64 + e) * 2) * 8 + i;
    W2[base]     = (unsigned short)hb;
    W2[base + 8] = (unsigned short)lb;
}

// ONE block = ONE 64-token tile, fully self-contained:
//   phase 1: 16 waves, wave (kw,tw) computes 16 tok x 64 exp over its 1024-d chunk
//            via 3-term bf16-split MFMA (hi*hi + hi*lo + lo*hi, fp32 accum).
//   phase 2: in-LDS split-K reduction (4 phases, plain +=, no atomics).
//   phase 3: softmax + top-9 + ambiguity flag (LDS-resident, no p[64] regs).
//   phase 4: inline fp64 repair of flagged tokens (block-cooperative).
// No global partials, no device-scope sync, no cross-block anything.
// Frag maps (R8-verified on HW): A row=lane&15, B col=lane&15, k=(lane>>4)*8+i;
// D col=lane&15 (expert), row=(lane>>4)*4+reg (token).
__global__ __launch_bounds__(NTHR)
void router_kernel(const float* __restrict__ x, const unsigned short* __restrict__ W2,
                   const float* __restrict__ W,
                   float* __restrict__ out_w, float* __restrict__ out_i,
                   float* __restrict__ out_p) {
    __shared__ float  lg[BLK_TOK * 65];   // 16.6 KB logits -> probs
    __shared__ float  xs[D_MODEL];        // 16 KB  (repair x row)
    __shared__ double ls[16][NEXP];       // 8 KB   (repair partials / scratch)
    __shared__ int    flg[BLK_TOK];
    __shared__ double sm2;                // repair max broadcast

    const int tid  = threadIdx.x;
    const int lane = tid & 63;
    const int wv   = __builtin_amdgcn_readfirstlane(tid >> 6);   // 0..15
    const int tw   = wv & 3;                             // token stripe
    const int kw   = wv >> 2;                            // K-chunk
    const int tok0 = blockIdx.x * BLK_TOK;
    const int kbase = kw * KC;

    const int l15 = lane & 15;
    const int kg  = lane >> 4;                           // k-group 0..3

    f32x4 acc[4];
#pragma unroll
    for (int nt = 0; nt < 4; ++nt) acc[nt] = (f32x4)0.f;

    const float* xrow = x + (size_t)(tok0 + tw * 16 + l15) * D_MODEL + kbase + kg * 8;
    const unsigned short* wbase = W2 + ((size_t)(((kbase >> 3) + kg) * 64 + l15) * 2) * 8;

#pragma unroll 2
    for (int ks = 0; ks < KC / 32; ++ks) {               // 32 K-steps of 32 d
        const float4 xa = *(const float4*)(xrow + ks * 32);
        const float4 xb = *(const float4*)(xrow + ks * 32 + 4);

        union { unsigned u[4]; bf16x8 v; } Ahi, Alo;
#pragma unroll
        for (int p = 0; p < 4; ++p) {
            const float f0 = (p == 0) ? xa.x : (p == 1) ? xa.z : (p == 2) ? xb.x : xb.z;
            const float f1 = (p == 0) ? xa.y : (p == 1) ? xa.w : (p == 2) ? xb.y : xb.w;
            const unsigned h0 = b16rne(f0), h1 = b16rne(f1);
            Ahi.u[p] = h0 | (h1 << 16);
            const float l0 = f0 - __uint_as_float(h0 << 16);
            const float l1 = f1 - __uint_as_float(h1 << 16);
            Alo.u[p] = b16rne(l0) | (b16rne(l1) << 16);
        }

        const unsigned short* wk = wbase + (size_t)ks * 4096;   // +4 kb-rows
#pragma unroll
        for (int nt = 0; nt < 4; ++nt) {
            const unsigned short* wp = wk + nt * 256;    // +16 experts
            const bf16x8 bhi = *(const bf16x8*)(wp);
            const bf16x8 blo = *(const bf16x8*)(wp + 8);
            acc[nt] = __builtin_amdgcn_mfma_f32_16x16x32_bf16(Ahi.v, bhi, acc[nt], 0, 0, 0);
            acc[nt] = __builtin_amdgcn_mfma_f32_16x16x32_bf16(Ahi.v, blo, acc[nt], 0, 0, 0);
            acc[nt] = __builtin_amdgcn_mfma_f32_16x16x32_bf16(Alo.v, bhi, acc[nt], 0, 0, 0);
        }
    }

    // ---- in-block split-K reduction: 4 phases of plain read-add-write ----
    for (int p = 0; p < 4; ++p) {
        if (kw == p) {
#pragma unroll
            for (int nt = 0; nt < 4; ++nt)
#pragma unroll
                for (int r = 0; r < 4; ++r) {
                    float* c = &lg[(tw * 16 + kg * 4 + r) * 65 + nt * 16 + l15];
                    if (p == 0) *c = acc[nt][r];
                    else       *c += acc[nt][r];
                }
        }
        __syncthreads();
    }

    // ---- finalize: softmax + top-9 + flag, LDS-resident (stride 65 = conflict-free) ----
    if (tid < 64) {
        const int tok = tok0 + tid;
        float m = -INFINITY;
#pragma unroll
        for (int e = 0; e < 64; ++e) m = fmaxf(m, lg[tid * 65 + e]);
        float z = 0.f;
#pragma unroll
        for (int e = 0; e < 64; ++e) {
            const float pe = __expf(lg[tid * 65 + e] - m);
            z += pe;
            lg[tid * 65 + e] = pe;
        }
        const float rz = 1.f / z;
#pragma unroll
        for (int e = 0; e < 64; ++e) lg[tid * 65 + e] *= rz;

        // branch-free top-9 (strict > => lowest index on ties, matching lax.top_k)
        float tv[9]; int ti[9];
#pragma unroll
        for (int k = 0; k < 9; ++k) { tv[k] = -1.f; ti[k] = 0; }
        for (int e = 0; e < 64; ++e) {
            float v = lg[tid * 65 + e]; int idx = e;
#pragma unroll
            for (int k = 0; k < 9; ++k) {
                const bool gt = v > tv[k];
                const float nv = gt ? v : tv[k];
                const int   ni = gt ? idx : ti[k];
                const float ov = gt ? tv[k] : v;
                const int   oi = gt ? ti[k] : idx;
                tv[k] = nv; ti[k] = ni; v = ov; idx = oi;
            }
        }
        // ambiguity flag: bf16-split logit err sigma ~1.5e-5 -> 4e-4 is >13 sigma
        int flag = 0;
#pragma unroll
        for (int k = 0; k < 8; ++k)
            if (tv[k] - tv[k + 1] <= tv[k] * 4e-4f + 1e-9f) flag = 1;
        flg[tid] = flag;

        float s8 = 0.f;
#pragma unroll
        for (int k = 0; k < 8; ++k) s8 += tv[k];
        const float denom = s8 + 1e-9f;
#pragma unroll
        for (int k = 0; k < 8; ++k) {
            out_w[tok * TOPK + k] = tv[k] / denom;
            out_i[tok * TOPK + k] = (float)ti[k];
        }
    }
    __syncthreads();

    // coalesced probs store: 1024 threads x 1 float4 = full 64x64 tile
    {
        const int t  = tid >> 4;
        const int e4 = (tid & 15) << 2;
        const float* src = &lg[t * 65 + e4];
        *(float4*)&out_p[(size_t)(tok0 + t) * NEXP + e4] =
            make_float4(src[0], src[1], src[2], src[3]);
    }

    // ---- inline fp64 repair of this tile's flagged tokens ----
    const int e = tid & 63;
    const int q = tid >> 6;              // d-16th 0..15 (256 d each)
    for (int t = 0; t < BLK_TOK; ++t) {
        if (!flg[t]) continue;           // uniform branch (LDS broadcast)
        __syncthreads();                 // protect xs/ls reuse across iterations
        const float4* xsrc = (const float4*)(x + (size_t)(tok0 + t) * D_MODEL);
        for (int v = tid; v < D_MODEL / 4; v += NTHR)
            ((float4*)xs)[v] = xsrc[v];
        __syncthreads();

        {
            const float* wrow = W + (size_t)e * D_MODEL + q * 256;
            const float* xr2 = xs + q * 256;
            double s0 = 0., s1 = 0., s2 = 0., s3 = 0.;
            for (int d = 0; d < 256; d += 4) {
                const float4 wv2 = *(const float4*)(wrow + d);
                const float4 xv2 = *(const float4*)(xr2 + d);
                s0 += (double)xv2.x * (double)wv2.x;
                s1 += (double)xv2.y * (double)wv2.y;
                s2 += (double)xv2.z * (double)wv2.z;
                s3 += (double)xv2.w * (double)wv2.w;
            }
            ls[q][e] = (s0 + s1) + (s2 + s3);
        }
        __syncthreads();

        if (tid < 64) {                  // lane e: fold 16 partials
            double v = 0.;
#pragma unroll
            for (int qq = 0; qq < 16; ++qq) v += ls[qq][tid];
            ls[0][tid] = v;
        }
        __syncthreads();
        if (tid == 0) {
            double m = -1e300;
            for (int k = 0; k < 64; ++k) m = ls[0][k] > m ? ls[0][k] : m;
            sm2 = m;
        }
        __syncthreads();
        if (tid < 64) ls[1][tid] = exp(ls[0][tid] - sm2);   // wave-parallel fp64 exp
        __syncthreads();
        if (tid == 0) {
            double Z = 0.;
            for (int k = 0; k < 64; ++k) Z += ls[1][k];
            double tv[8]; int ti[8];
            for (int k = 0; k < 8; ++k) { tv[k] = -1.; ti[k] = 0; }
            for (int k = 0; k < 64; ++k) {
                double v = ls[1][k] / Z; int idx = k;
                for (int u = 0; u < 8; ++u) {
                    const bool gt = v > tv[u];
                    const double nv = gt ? v : tv[u];
                    const int    ni = gt ? idx : ti[u];
                    const double ov = gt ? tv[u] : v;
                    const int    oi = gt ? ti[u] : idx;
                    tv[u] = nv; ti[u] = ni; v = ov; idx = oi;
                }
            }
            double s8 = 0.;
            for (int k = 0; k < 8; ++k) s8 += tv[k];
            const double denom = s8 + 1e-9;
            const int tok = tok0 + t;
            for (int k = 0; k < 8; ++k) {
                out_w[tok * TOPK + k] = (float)(tv[k] / denom);
                out_i[tok * TOPK + k] = (float)ti[k];
            }
        }
    }
}

extern "C" void kernel_launch(void* const* d_in, const int* in_sizes, int n_in,
                              void* d_out, int out_size, void* d_ws, size_t ws_size,
                              hipStream_t stream) {
    const float* x = (const float*)d_in[0];   // [4,4096,4096]
    const float* W = (const float*)d_in[1];   // [64,4096]

    unsigned short* W2 = (unsigned short*)d_ws;          // 1 MB (bf16 hi/lo)

    float* out   = (float*)d_out;
    float* out_w = out;                       // [16384,8]
    float* out_i = out + NTOK * TOPK;         // [16384,8] (as float)
    float* out_p = out + 2 * NTOK * TOPK;     // [16384,64]

    prep_kernel<<<262144 / 256, 256, 0, stream>>>(W, W2);
    router_kernel<<<NTOK / BLK_TOK, NTHR, 0, stream>>>(x, W2, W, out_w, out_i, out_p);
}